// Round 9
// baseline (5672.610 us; speedup 1.0000x reference)
//
#include <hip/hip_runtime.h>
#include <math.h>

// ---------------------------------------------------------------------------
// DisableGateLSTM R13: A/B chain-split pipeline, NO LDS pad (= R12 minus
// SHPAD). Empirical rule from 7 submissions: all 3 kernels with LDS>80KiB
// "container failed twice"; all 4 at 71168B ran. Pad dropped; LDS footprint
// returns to the 4x-verified 71168B.
//
// Theory (unchanged): R4->R9 (halve LDS work) ~no-op; R10/R11 (sync
// mechanism) hurt -> the wall is the EXCHANGE ROUND-TRIP serialized each
// step: gates -> h store -> LLC visibility -> poll -> h load -> GEMM.
// The 16 chains/group are independent; split A=0..7, B=8..15:
//   step t: GEMM_A(t);red_A;gates_A -> h_A(t+1), flagA
//           [poll B(t); stage h_B(t)]            <- hid under phase A
//           GEMM_B(t);red_B;gates_B -> h_B(t+1), flagB
//           [poll A(t+1); stage h_A(t+1), x_{t+1}] <- hid under phase B
// Each set's exchange has a full opposite-set compute phase between flag
// and poll. Deadlock-checked by induction: A-arrival(t) gated only on
// genA>=t (all A(t-1)); wait-genB>=t needs only B(t-1); no cycle.
// Numerics: chain split only; per-output FMA order identical to R9 ->
// absmax 0.0. R9-proven pieces verbatim: tid==0 cnt/gen poll (x2),
// staging (32 lanes/chain, 8 b64), GEMM+dpp8+scatter, reduce order
// (bias + w ascending), exact libm gates, wmax/head.
//  * Weights in VGPRs (48 f/thread). PRS=68 bank-derived -- don't change.
// ---------------------------------------------------------------------------

#define BATCH   64
#define SEQ     512
#define EMBED   256
#define HIDDEN  512
#define GD      768
#define CLASSES 4

#define NBLK    256
#define NTHR    512
#define GROUPS  4
#define GB      64
#define CPG     16
#define UPB     8
#define ROWS    32
#define SETC    8      // chains per pipeline half-set

// LDS strides (floats)
#define SHS  520   // sH chain stride: 512 + 8
#define SXS  264   // sX chain stride: 256 + 8
#define PRS  68    // partial-scratch rank stride (bank-derived)

typedef unsigned long long __attribute__((may_alias)) ull_a;

union F2U { float f[2]; unsigned long long u; };

// Sum over each aligned 8-lane group via DPP involutions (VALU pipe, no LDS).
__device__ __forceinline__ float dpp8_sum(float v) {
  int x;
  x = __builtin_amdgcn_update_dpp(0, __float_as_int(v), 0x141, 0xF, 0xF, false); // row_half_mirror
  v += __int_as_float(x);
  x = __builtin_amdgcn_update_dpp(0, __float_as_int(v), 0x4E,  0xF, 0xF, false); // quad_perm(2,3,0,1)
  v += __int_as_float(x);
  x = __builtin_amdgcn_update_dpp(0, __float_as_int(v), 0xB1,  0xF, 0xF, false); // quad_perm(1,0,3,2)
  v += __int_as_float(x);
  return v;
}

__global__ __launch_bounds__(NTHR) void lstm_persistent(
    const int*   __restrict__ ids,
    const float* __restrict__ emb,
    const float* __restrict__ Wf, const float* __restrict__ bf,
    const float* __restrict__ Wi, const float* __restrict__ bi,
    const float* __restrict__ Wo, const float* __restrict__ bo,
    const float* __restrict__ Wc, const float* __restrict__ bc,
    const float* __restrict__ fcw,
    const float* __restrict__ fcb,
    float* __restrict__ out,
    float* __restrict__ ws)
{
  __shared__ __align__(16) float sH[CPG * SHS];      // 33.3 KB
  __shared__ __align__(16) float sX[CPG * SXS];      // 16.9 KB
  __shared__ __align__(16) float sPart[64 * PRS];    // 17.4 KB
  __shared__ float sG[ROWS][CPG];                    // pre-acts + head scratch
  __shared__ float sC[UPB][CPG];
  __shared__ float sM[UPB][CPG];
  __shared__ float sB[ROWS];

  const int tid = threadIdx.x;
  const int bid = blockIdx.x;
  const int g   = bid & 3;
  const int j   = bid >> 2;
  const int u0  = j * UPB;

  float*    hbufF   = ws;                                    // [2][64][512] f32
  ull_a*    hbufU   = (ull_a*)ws;                            // same, ull view
  float*    wmaxF   = ws + (size_t)2 * BATCH * HIDDEN;       // [64][512] f32
  ull_a*    wmaxU   = (ull_a*)wmaxF;
  // barrier region (4KB, memset 0): [cntA][genA][cntB][genB] x [4 groups][64]
  unsigned* barArea = (unsigned*)(ws + (size_t)3 * BATCH * HIDDEN);
  unsigned* cntA = barArea + g * 64;
  unsigned* genA = barArea + 256 + g * 64;
  unsigned* cntB = barArea + 512 + g * 64;
  unsigned* genB = barArea + 768 + g * 64;

  // ---- thread geometry (R9) ----
  const int sl = tid & 7;
  const int wv = tid >> 6;
  const int s  = sl + wv * 8;          // 0..63
  const int rg = (tid >> 3) & 7;       // 0..7

  // ---- weights -> VGPRs, once (48 floats/thread, no redundancy) ----
  float4 wh[4][2], wx4[4];
  {
    const float* Wg = (rg < 2) ? Wf : (rg < 4) ? Wi : (rg < 6) ? Wo : Wc;
    const int ub = u0 + (rg & 1) * 4;
    #pragma unroll
    for (int ri = 0; ri < 4; ++ri) {
      const float* row = Wg + (size_t)(ub + ri) * GD;
      wh[ri][0] = *(const float4*)(row + s * 8);
      wh[ri][1] = *(const float4*)(row + s * 8 + 4);
      wx4[ri]   = *(const float4*)(row + HIDDEN + s * 4);
    }
  }
  if (tid < ROWS) {
    const float* bv = (tid < 8) ? bf : (tid < 16) ? bi : (tid < 24) ? bo : bc;
    sB[tid] = bv[u0 + (tid & 7)];
  }
  if (tid < UPB * CPG) {
    ((float*)sC)[tid] = 0.0f;
    ((float*)sM)[tid] = -3.402823e38f;
  }

  // staging mapping (chain-major, 32 lanes/chain; R9-proven pattern)
  const int stg_c = tid >> 5;          // 0..15 (A: 0..7 on tid<256, B: 8..15)
  const int stg_s = tid & 31;
  const int bStg  = g * CPG + stg_c;

  const float* pH = sH + s * 8;
  const float* pX = sX + s * 4;

  // ---- preamble: prefetch+stage x_0; stage h_A(0)=0 from hbuf[0] ----
  float4 rx0, rx1;
  {
    int id0 = ids[(size_t)bStg * SEQ];
    const float4* xs = (const float4*)(emb + (size_t)id0 * EMBED);
    rx0 = xs[stg_s * 2];
    rx1 = xs[stg_s * 2 + 1];
    float* dx = sX + stg_c * SXS + stg_s * 8;
    *(float4*)dx = rx0;
    *(float4*)(dx + 4) = rx1;
  }
  if (tid < 256) {   // stage h_A(0) (zeros)
    const ull_a* hs = hbufU + (size_t)bStg * (HIDDEN / 2);
    float* dh = sH + stg_c * SHS;
    #pragma unroll
    for (int kk = 0; kk < 8; ++kk) {
      unsigned long long v = __hip_atomic_load(hs + stg_s + kk * 32,
                                               __ATOMIC_RELAXED,
                                               __HIP_MEMORY_SCOPE_AGENT);
      *(ull_a*)(dh + 2 * stg_s + 64 * kk) = v;
    }
  }
  __syncthreads();

  for (int t = 0; t < SEQ; ++t) {
    const int pb = t & 1;

    // ================= PHASE A (chains 0..7) =================
    #pragma unroll
    for (int ci = 0; ci < SETC; ++ci) {
      float4 xv = *(const float4*)(pX + ci * SXS);
      float4 h0 = *(const float4*)(pH + ci * SHS);
      float4 h1 = *(const float4*)(pH + ci * SHS + 4);
      float a[4];
      #pragma unroll
      for (int ri = 0; ri < 4; ++ri) {
        float t0;
        t0 = wx4[ri].x * xv.x;
        t0 = fmaf(wx4[ri].y, xv.y, t0);
        t0 = fmaf(wx4[ri].z, xv.z, t0);
        t0 = fmaf(wx4[ri].w, xv.w, t0);
        t0 = fmaf(wh[ri][0].x, h0.x, t0);
        t0 = fmaf(wh[ri][0].y, h0.y, t0);
        t0 = fmaf(wh[ri][0].z, h0.z, t0);
        t0 = fmaf(wh[ri][0].w, h0.w, t0);
        t0 = fmaf(wh[ri][1].x, h1.x, t0);
        t0 = fmaf(wh[ri][1].y, h1.y, t0);
        t0 = fmaf(wh[ri][1].z, h1.z, t0);
        t0 = fmaf(wh[ri][1].w, h1.w, t0);
        a[ri] = dpp8_sum(t0);
      }
      if ((tid & 7) == 0) {
        float* dst = sPart + (tid >> 3) * PRS + ci;   // R9 scatter layout
        dst[0]  = a[0];
        dst[16] = a[1];
        dst[32] = a[2];
        dst[48] = a[3];
      }
    }
    __syncthreads();                                   // A1: sPart ready
    if (tid < 256) {                                   // reduce A (4 waves)
      const int rr  = tid >> 3;            // row 0..31
      const int ci2 = tid & 7;             // chain 0..7
      const int rg2 = rr >> 2, ril = rr & 3;
      float ssum = sB[rr];
      #pragma unroll
      for (int w = 0; w < 8; ++w)
        ssum += sPart[(w * 8 + rg2) * PRS + ril * 16 + ci2];
      sG[rr][ci2] = ssum;
    }
    __syncthreads();                                   // A2: sG ready
    if (tid < 64) {                                    // gates A (exact libm)
      const int u = tid & 7, ch = tid >> 3;            // ch 0..7
      float pf = sG[u][ch];
      float pi = sG[8 + u][ch];
      float po = sG[16 + u][ch];
      float pg = sG[24 + u][ch];
      float f  = 1.0f / (1.0f + expf(-pf));
      float i_ = 1.0f / (1.0f + expf(-pi));
      float o  = 1.0f / (1.0f + expf(-po));
      float gg = tanhf(pg);
      float cn = f * sC[u][ch] + i_ * gg;
      float h  = o * tanhf(cn);
      sC[u][ch] = cn;
      sM[u][ch] = fmaxf(sM[u][ch], h);
      __hip_atomic_store(
          hbufF + ((size_t)(pb ^ 1) * BATCH + g * CPG + ch) * HIDDEN + u0 + u,
          h, __ATOMIC_RELAXED, __HIP_MEMORY_SCOPE_AGENT);
    }
    __syncthreads();                                   // A3: drain h_A stores
    if (tid == 0) {
      unsigned old = __hip_atomic_fetch_add(cntA, 1u, __ATOMIC_RELAXED,
                                            __HIP_MEMORY_SCOPE_AGENT);
      if (old == (unsigned)((t + 1) * GB - 1))
        __hip_atomic_store(genA, (unsigned)(t + 1), __ATOMIC_RELAXED,
                           __HIP_MEMORY_SCOPE_AGENT);
      // poll B(t): flagged during prev iteration's phase B (a full phase ago)
      while (__hip_atomic_load(genB, __ATOMIC_RELAXED,
                               __HIP_MEMORY_SCOPE_AGENT) < (unsigned)t)
        __builtin_amdgcn_s_sleep(1);
    }
    __atomic_signal_fence(__ATOMIC_ACQUIRE);
    __syncthreads();                                   // B1: h_B(t) visible
    if (tid >= 256) {                                  // stage h_B(t), rows 8..15
      const ull_a* hs = hbufU + ((size_t)pb * BATCH + bStg) * (HIDDEN / 2);
      float* dh = sH + stg_c * SHS;
      #pragma unroll
      for (int kk = 0; kk < 8; ++kk) {
        unsigned long long v = __hip_atomic_load(hs + stg_s + kk * 32,
                                                 __ATOMIC_RELAXED,
                                                 __HIP_MEMORY_SCOPE_AGENT);
        *(ull_a*)(dh + 2 * stg_s + 64 * kk) = v;
      }
    }
    __syncthreads();                                   // B2: sH_B ready

    // ================= PHASE B (chains 8..15) =================
    #pragma unroll
    for (int k = 0; k < SETC; ++k) {
      const int ci = SETC + k;
      float4 xv = *(const float4*)(pX + ci * SXS);
      float4 h0 = *(const float4*)(pH + ci * SHS);
      float4 h1 = *(const float4*)(pH + ci * SHS + 4);
      float a[4];
      #pragma unroll
      for (int ri = 0; ri < 4; ++ri) {
        float t0;
        t0 = wx4[ri].x * xv.x;
        t0 = fmaf(wx4[ri].y, xv.y, t0);
        t0 = fmaf(wx4[ri].z, xv.z, t0);
        t0 = fmaf(wx4[ri].w, xv.w, t0);
        t0 = fmaf(wh[ri][0].x, h0.x, t0);
        t0 = fmaf(wh[ri][0].y, h0.y, t0);
        t0 = fmaf(wh[ri][0].z, h0.z, t0);
        t0 = fmaf(wh[ri][0].w, h0.w, t0);
        t0 = fmaf(wh[ri][1].x, h1.x, t0);
        t0 = fmaf(wh[ri][1].y, h1.y, t0);
        t0 = fmaf(wh[ri][1].z, h1.z, t0);
        t0 = fmaf(wh[ri][1].w, h1.w, t0);
        a[ri] = dpp8_sum(t0);
      }
      if ((tid & 7) == 0) {
        float* dst = sPart + (tid >> 3) * PRS + ci;
        dst[0]  = a[0];
        dst[16] = a[1];
        dst[32] = a[2];
        dst[48] = a[3];
      }
    }
    // prefetch x_{t+1} (hides under reduce/gates B)
    {
      const int tn = (t + 1 < SEQ) ? t + 1 : SEQ - 1;
      int idn = ids[(size_t)bStg * SEQ + tn];
      const float4* xs = (const float4*)(emb + (size_t)idn * EMBED);
      rx0 = xs[stg_s * 2];
      rx1 = xs[stg_s * 2 + 1];
    }
    __syncthreads();                                   // B3: sPart ready
    if (tid < 256) {                                   // reduce B
      const int rr  = tid >> 3;
      const int ci2 = SETC + (tid & 7);                // chain 8..15
      const int rg2 = rr >> 2, ril = rr & 3;
      float ssum = sB[rr];
      #pragma unroll
      for (int w = 0; w < 8; ++w)
        ssum += sPart[(w * 8 + rg2) * PRS + ril * 16 + ci2];
      sG[rr][ci2] = ssum;
    }
    __syncthreads();                                   // B4
    if (tid < 64) {                                    // gates B
      const int u = tid & 7, ch = SETC + (tid >> 3);   // ch 8..15
      float pf = sG[u][ch];
      float pi = sG[8 + u][ch];
      float po = sG[16 + u][ch];
      float pg = sG[24 + u][ch];
      float f  = 1.0f / (1.0f + expf(-pf));
      float i_ = 1.0f / (1.0f + expf(-pi));
      float o  = 1.0f / (1.0f + expf(-po));
      float gg = tanhf(pg);
      float cn = f * sC[u][ch] + i_ * gg;
      float h  = o * tanhf(cn);
      sC[u][ch] = cn;
      sM[u][ch] = fmaxf(sM[u][ch], h);
      __hip_atomic_store(
          hbufF + ((size_t)(pb ^ 1) * BATCH + g * CPG + ch) * HIDDEN + u0 + u,
          h, __ATOMIC_RELAXED, __HIP_MEMORY_SCOPE_AGENT);
    }
    __syncthreads();                                   // B5: drain h_B stores
    if (tid == 0) {
      unsigned old = __hip_atomic_fetch_add(cntB, 1u, __ATOMIC_RELAXED,
                                            __HIP_MEMORY_SCOPE_AGENT);
      if (old == (unsigned)((t + 1) * GB - 1))
        __hip_atomic_store(genB, (unsigned)(t + 1), __ATOMIC_RELAXED,
                           __HIP_MEMORY_SCOPE_AGENT);
      // poll A(t+1): flagged during THIS iteration's phase A (a phase ago)
      while (__hip_atomic_load(genA, __ATOMIC_RELAXED,
                               __HIP_MEMORY_SCOPE_AGENT) < (unsigned)(t + 1))
        __builtin_amdgcn_s_sleep(1);
    }
    __atomic_signal_fence(__ATOMIC_ACQUIRE);
    __syncthreads();                                   // E1: h_A(t+1) visible

    // ---- stage x_{t+1} (all) + h_A(t+1) (rows 0..7) ----
    {
      float* dx = sX + stg_c * SXS + stg_s * 8;
      *(float4*)dx = rx0;
      *(float4*)(dx + 4) = rx1;
    }
    if (tid < 256) {
      const ull_a* hs = hbufU + ((size_t)((t + 1) & 1) * BATCH + bStg) * (HIDDEN / 2);
      float* dh = sH + stg_c * SHS;
      #pragma unroll
      for (int kk = 0; kk < 8; ++kk) {
        unsigned long long v = __hip_atomic_load(hs + stg_s + kk * 32,
                                                 __ATOMIC_RELAXED,
                                                 __HIP_MEMORY_SCOPE_AGENT);
        *(ull_a*)(dh + 2 * stg_s + 64 * kk) = v;
      }
    }
    __syncthreads();                                   // E2: ready for next iter
  }

  // ---- publish running max (coherent), final arrival on cntA ----
  if (tid < 128) {
    const int u = tid & 7, ch = tid >> 3;
    __hip_atomic_store(wmaxF + (size_t)(g * CPG + ch) * HIDDEN + u0 + u,
                       sM[u][ch], __ATOMIC_RELAXED, __HIP_MEMORY_SCOPE_AGENT);
  }
  __syncthreads();   // drains vmcnt for wmax stores
  if (tid == 0) {
    unsigned old = __hip_atomic_fetch_add(cntA, 1u, __ATOMIC_RELAXED,
                                          __HIP_MEMORY_SCOPE_AGENT);
    if (old == (unsigned)((SEQ + 1) * GB - 1))
      __hip_atomic_store(genA, (unsigned)(SEQ + 1), __ATOMIC_RELAXED,
                         __HIP_MEMORY_SCOPE_AGENT);
  }

  // ---- head GEMV on group-leader blocks ----
  if (j == 0) {
    if (tid == 0) {
      while (__hip_atomic_load(genA, __ATOMIC_RELAXED,
                               __HIP_MEMORY_SCOPE_AGENT) < (unsigned)(SEQ + 1))
        __builtin_amdgcn_s_sleep(1);
    }
    __atomic_signal_fence(__ATOMIC_ACQUIRE);
    __syncthreads();

    const int ch = tid & 15, cls = (tid >> 4) & 3, us = tid >> 6;
    const ull_a* mrow = wmaxU + (size_t)(g * CPG + ch) * (HIDDEN / 2) + us * 32;
    const float* wrow = fcw + (size_t)cls * HIDDEN + us * 64;
    float sacc = 0.0f;
    for (int q = 0; q < 32; ++q) {
      F2U v;
      v.u = __hip_atomic_load(mrow + q, __ATOMIC_RELAXED,
                              __HIP_MEMORY_SCOPE_AGENT);
      sacc = fmaf(v.f[0], wrow[2 * q], sacc);
      sacc = fmaf(v.f[1], wrow[2 * q + 1], sacc);
    }
    float* red2 = &sG[0][0];
    red2[tid] = sacc;
    __syncthreads();
    if (tid < 64) {
      float tot = fcb[(tid >> 4) & 3];
      #pragma unroll
      for (int q = 0; q < 8; ++q) tot += red2[q * 64 + tid];
      out[(g * CPG + (tid & 15)) * CLASSES + ((tid >> 4) & 3)] = tot;
    }
  }
}

extern "C" void kernel_launch(void* const* d_in, const int* in_sizes, int n_in,
                              void* d_out, int out_size, void* d_ws, size_t ws_size,
                              hipStream_t stream) {
  const int*   ids = (const int*)  d_in[0];
  const float* emb = (const float*)d_in[1];
  const float* Wf  = (const float*)d_in[2];
  const float* bf  = (const float*)d_in[3];
  const float* Wi  = (const float*)d_in[4];
  const float* bi  = (const float*)d_in[5];
  const float* Wo  = (const float*)d_in[6];
  const float* bo  = (const float*)d_in[7];
  const float* Wc  = (const float*)d_in[8];
  const float* bc  = (const float*)d_in[9];
  const float* fcw = (const float*)d_in[10];
  const float* fcb = (const float*)d_in[11];

  // zero h0 (hbuf buffer 0) and the barrier region (cntA/genA/cntB/genB)
  hipMemsetAsync(d_ws, 0, (size_t)BATCH * HIDDEN * sizeof(float), stream);
  hipMemsetAsync((char*)d_ws + (size_t)3 * BATCH * HIDDEN * sizeof(float),
                 0, 4096, stream);

  lstm_persistent<<<dim3(NBLK), dim3(NTHR), 0, stream>>>(
      ids, emb, Wf, bf, Wi, bi, Wo, bo, Wc, bc, fcw, fcb,
      (float*)d_out, (float*)d_ws);
}

// Round 10
// 3772.821 us; speedup vs baseline: 1.5035x; 1.5035x over previous
//
#include <hip/hip_runtime.h>
#include <math.h>

// ---------------------------------------------------------------------------
// DisableGateLSTM R14: R9 + {wide activations, flag-array arrival with
// single-wave poll}. 256 blocks x 512 threads, 1 block/CU. 4 groups x 64
// blocks; group g owns chains [16g,16g+16); block j owns units [8j,8j+8).
//
// Standings: R9=4330 (best), R10=4686 (narrow fused phase), R11=4590
// (flags + 512 wave-pollers + wide act bundled), R13=5754 (A/B split).
// Lessons: keep phases 512-wide; don't multiply barriers; don't let all
// 8 waves spin on flags. R14 isolates the two untested levers on R9:
//  (a) activations (3 sigmoid + 1 tanh) computed in the 512-wide reduce
//      phase (wave-uniform rr<24 branch); narrow 128-thread phase is just
//      cn=f*c+i*g, h=o*tanhf(cn), store -> h hits LLC sooner.
//  (b) arrival: producer stores flag[j]=t+1 on a PRIVATE 64B line (kills
//      the 64-deep same-line fetch_add chain); ONLY wave 0 polls (lane l
//      reads block l's flag, __all(v>=t)), others wait at the barrier ->
//      1/8 of R11's poll pressure.
// Numerics: same activation exprs, same inputs, same order -> bit-identical
// to R9 (absmax 0.0). Everything else R9 verbatim: staging (32 lanes/chain,
// 8 b64), GEMM+dpp8+scatter (sPart[rank][ri*16+ci], conflicts 2.9e7),
// reduce order (bias + w ascending), wmax/head.
//  * Weights in VGPRs (48 f/thread). PRS=68 bank-derived -- don't change.
//  * LDS 71168B -- the 4x-verified footprint; >80KiB fails the harness.
// ---------------------------------------------------------------------------

#define BATCH   64
#define SEQ     512
#define EMBED   256
#define HIDDEN  512
#define GD      768
#define CLASSES 4

#define NBLK    256
#define NTHR    512
#define GROUPS  4
#define GB      64
#define CPG     16
#define UPB     8
#define ROWS    32

// LDS strides (floats)
#define SHS  520   // sH chain stride: 512 + 8
#define SXS  264   // sX chain stride: 256 + 8
#define PRS  68    // partial-scratch rank stride (bank-derived)

typedef unsigned long long __attribute__((may_alias)) ull_a;

union F2U { float f[2]; unsigned long long u; };

// Sum over each aligned 8-lane group via DPP involutions (VALU pipe, no LDS).
__device__ __forceinline__ float dpp8_sum(float v) {
  int x;
  x = __builtin_amdgcn_update_dpp(0, __float_as_int(v), 0x141, 0xF, 0xF, false); // row_half_mirror
  v += __int_as_float(x);
  x = __builtin_amdgcn_update_dpp(0, __float_as_int(v), 0x4E,  0xF, 0xF, false); // quad_perm(2,3,0,1)
  v += __int_as_float(x);
  x = __builtin_amdgcn_update_dpp(0, __float_as_int(v), 0xB1,  0xF, 0xF, false); // quad_perm(1,0,3,2)
  v += __int_as_float(x);
  return v;
}

__global__ __launch_bounds__(NTHR) void lstm_persistent(
    const int*   __restrict__ ids,
    const float* __restrict__ emb,
    const float* __restrict__ Wf, const float* __restrict__ bf,
    const float* __restrict__ Wi, const float* __restrict__ bi,
    const float* __restrict__ Wo, const float* __restrict__ bo,
    const float* __restrict__ Wc, const float* __restrict__ bc,
    const float* __restrict__ fcw,
    const float* __restrict__ fcb,
    float* __restrict__ out,
    float* __restrict__ ws)
{
  __shared__ __align__(16) float sH[CPG * SHS];      // 33.3 KB
  __shared__ __align__(16) float sX[CPG * SXS];      // 16.9 KB
  __shared__ __align__(16) float sPart[64 * PRS];    // 17.4 KB
  __shared__ float sG[ROWS][CPG];                    // activations + head scratch
  __shared__ float sC[UPB][CPG];
  __shared__ float sM[UPB][CPG];
  __shared__ float sB[ROWS];

  const int tid = threadIdx.x;
  const int bid = blockIdx.x;
  const int g   = bid & 3;
  const int j   = bid >> 2;
  const int u0  = j * UPB;

  float*    hbufF   = ws;                                    // [2][64][512] f32
  ull_a*    hbufU   = (ull_a*)ws;                            // same, ull view
  float*    wmaxF   = ws + (size_t)2 * BATCH * HIDDEN;       // [64][512] f32
  ull_a*    wmaxU   = (ull_a*)wmaxF;
  // flags: [4 groups][64 blocks] x 64B-stride lines (16 u32) = 16 KB, memset 0
  unsigned* flags   = (unsigned*)(ws + (size_t)3 * BATCH * HIDDEN);
  unsigned* myflag  = flags + (g * 64 + j) * 16;

  // ---- thread geometry (R9) ----
  const int sl = tid & 7;
  const int wv = tid >> 6;
  const int s  = sl + wv * 8;          // 0..63
  const int rg = (tid >> 3) & 7;       // 0..7

  // ---- weights -> VGPRs, once (48 floats/thread, no redundancy) ----
  float4 wh[4][2], wx4[4];
  {
    const float* Wg = (rg < 2) ? Wf : (rg < 4) ? Wi : (rg < 6) ? Wo : Wc;
    const int ub = u0 + (rg & 1) * 4;
    #pragma unroll
    for (int ri = 0; ri < 4; ++ri) {
      const float* row = Wg + (size_t)(ub + ri) * GD;
      wh[ri][0] = *(const float4*)(row + s * 8);
      wh[ri][1] = *(const float4*)(row + s * 8 + 4);
      wx4[ri]   = *(const float4*)(row + HIDDEN + s * 4);
    }
  }
  if (tid < ROWS) {
    const float* bv = (tid < 8) ? bf : (tid < 16) ? bi : (tid < 24) ? bo : bc;
    sB[tid] = bv[u0 + (tid & 7)];
  }
  if (tid < UPB * CPG) {
    ((float*)sC)[tid] = 0.0f;
    ((float*)sM)[tid] = -3.402823e38f;
  }

  // staging mapping (chain-major, 32 lanes/chain; R9-proven pattern)
  const int stg_c = tid >> 5;
  const int stg_s = tid & 31;
  const int bStg  = g * CPG + stg_c;

  const float* pH = sH + s * 8;        // + ci*SHS via imm offsets
  const float* pX = sX + s * 4;

  // prefetch x_0 into registers
  float4 rx0, rx1;
  {
    int id0 = ids[(size_t)bStg * SEQ];
    const float4* xs = (const float4*)(emb + (size_t)id0 * EMBED);
    rx0 = xs[stg_s * 2];
    rx1 = xs[stg_s * 2 + 1];
  }

  for (int t = 0; t < SEQ; ++t) {
    const int pb = t & 1;

    // ---- stage x_t (register -> LDS); ordered vs GEMM reads by B2 ----
    {
      float* dx = sX + stg_c * SXS + stg_s * 8;
      *(float4*)dx = rx0;
      *(float4*)(dx + 4) = rx1;
    }

    // ---- wait for h_t: wave 0 polls 64 per-block flags (lane l <-> block
    //      l); other waves proceed to the barrier. Relaxed, no cache maint. ----
    if (tid < 64) {
      const unsigned* pf = flags + (g * 64 + tid) * 16;
      while (true) {
        unsigned v = __hip_atomic_load(pf, __ATOMIC_RELAXED,
                                       __HIP_MEMORY_SCOPE_AGENT);
        if (__all((int)(v >= (unsigned)t))) break;
        __builtin_amdgcn_s_sleep(1);
      }
    }
    __atomic_signal_fence(__ATOMIC_ACQUIRE);
    __syncthreads();                                   // B1: h_t published

    // ---- stage h_t via coherent loads ----
    {
      const ull_a* hs = hbufU + ((size_t)pb * BATCH + bStg) * (HIDDEN / 2);
      float* dh = sH + stg_c * SHS;
      #pragma unroll
      for (int kk = 0; kk < 8; ++kk) {
        unsigned long long v = __hip_atomic_load(hs + stg_s + kk * 32,
                                                 __ATOMIC_RELAXED,
                                                 __HIP_MEMORY_SCOPE_AGENT);
        *(ull_a*)(dh + 2 * stg_s + 64 * kk) = v;
      }
    }
    __syncthreads();                                   // B2: sX + sH ready

    // ---- fused x+h GEMM + DPP k-reduce + partial scatter (R9 verbatim) ----
    #pragma unroll
    for (int ci = 0; ci < 16; ++ci) {
      float4 xv = *(const float4*)(pX + ci * SXS);
      float4 h0 = *(const float4*)(pH + ci * SHS);
      float4 h1 = *(const float4*)(pH + ci * SHS + 4);
      float a[4];
      #pragma unroll
      for (int ri = 0; ri < 4; ++ri) {
        float t0;
        t0 = wx4[ri].x * xv.x;
        t0 = fmaf(wx4[ri].y, xv.y, t0);
        t0 = fmaf(wx4[ri].z, xv.z, t0);
        t0 = fmaf(wx4[ri].w, xv.w, t0);
        t0 = fmaf(wh[ri][0].x, h0.x, t0);
        t0 = fmaf(wh[ri][0].y, h0.y, t0);
        t0 = fmaf(wh[ri][0].z, h0.z, t0);
        t0 = fmaf(wh[ri][0].w, h0.w, t0);
        t0 = fmaf(wh[ri][1].x, h1.x, t0);
        t0 = fmaf(wh[ri][1].y, h1.y, t0);
        t0 = fmaf(wh[ri][1].z, h1.z, t0);
        t0 = fmaf(wh[ri][1].w, h1.w, t0);
        a[ri] = dpp8_sum(t0);
      }
      if ((tid & 7) == 0) {
        float* dst = sPart + (tid >> 3) * PRS + ci;   // R9 scatter layout
        dst[0]  = a[0];
        dst[16] = a[1];
        dst[32] = a[2];
        dst[48] = a[3];
      }
    }

    // ---- prefetch x_{t+1} (latency hides under reduce+update) ----
    {
      const int tn = (t + 1 < SEQ) ? t + 1 : SEQ - 1;
      int idn = ids[(size_t)bStg * SEQ + tn];
      const float4* xs = (const float4*)(emb + (size_t)idn * EMBED);
      rx0 = xs[stg_s * 2];
      rx1 = xs[stg_s * 2 + 1];
    }
    __syncthreads();                                   // B3: sPart ready

    // ---- 512-wide: cross-wave reduce (R9 order: bias + w ascending) +
    //      ACTIVATION (wave-uniform: rows 0-23 sigmoid, 24-31 tanh) ----
    {
      const int rr  = tid >> 4;            // row 0..31
      const int ci2 = tid & 15;            // chain
      const int rg2 = rr >> 2;
      const int idx = (rr & 3) * 16 + ci2;
      float ssum = sB[rr];
      #pragma unroll
      for (int w = 0; w < 8; ++w)
        ssum += sPart[(w * 8 + rg2) * PRS + idx];
      sG[rr][ci2] = (rr < 24) ? 1.0f / (1.0f + expf(-ssum)) : tanhf(ssum);
    }
    __syncthreads();                                   // B4: sG (acts) ready

    // ---- narrow phase (minimal): state update + coherent h store ----
    if (tid < 128) {
      const int u = tid & 7, ch = tid >> 3;
      float f  = sG[u][ch];
      float i_ = sG[8 + u][ch];
      float o  = sG[16 + u][ch];
      float gg = sG[24 + u][ch];
      float cn = f * sC[u][ch] + i_ * gg;
      float h  = o * tanhf(cn);
      sC[u][ch] = cn;
      sM[u][ch] = fmaxf(sM[u][ch], h);
      __hip_atomic_store(
          hbufF + ((size_t)(pb ^ 1) * BATCH + g * CPG + ch) * HIDDEN + u0 + u,
          h, __ATOMIC_RELAXED, __HIP_MEMORY_SCOPE_AGENT);
    }
    __syncthreads();   // B5: storers drain vmcnt -> h coherence-visible

    // ---- arrival: parallel per-block flag on a private 64B line ----
    if (tid == 0)
      __hip_atomic_store(myflag, (unsigned)(t + 1), __ATOMIC_RELAXED,
                         __HIP_MEMORY_SCOPE_AGENT);
  }

  // ---- publish running max (coherent), final flag ----
  if (tid < 128) {
    const int u = tid & 7, ch = tid >> 3;
    __hip_atomic_store(wmaxF + (size_t)(g * CPG + ch) * HIDDEN + u0 + u,
                       sM[u][ch], __ATOMIC_RELAXED, __HIP_MEMORY_SCOPE_AGENT);
  }
  __syncthreads();   // drains vmcnt for wmax stores
  if (tid == 0)
    __hip_atomic_store(myflag, (unsigned)(SEQ + 1), __ATOMIC_RELAXED,
                       __HIP_MEMORY_SCOPE_AGENT);

  // ---- head GEMV on group-leader blocks ----
  if (j == 0) {
    if (tid < 64) {
      const unsigned* pf = flags + (g * 64 + tid) * 16;
      while (true) {
        unsigned v = __hip_atomic_load(pf, __ATOMIC_RELAXED,
                                       __HIP_MEMORY_SCOPE_AGENT);
        if (__all((int)(v >= (unsigned)(SEQ + 1)))) break;
        __builtin_amdgcn_s_sleep(1);
      }
    }
    __atomic_signal_fence(__ATOMIC_ACQUIRE);
    __syncthreads();

    const int ch = tid & 15, cls = (tid >> 4) & 3, us = tid >> 6;
    const ull_a* mrow = wmaxU + (size_t)(g * CPG + ch) * (HIDDEN / 2) + us * 32;
    const float* wrow = fcw + (size_t)cls * HIDDEN + us * 64;
    float sacc = 0.0f;
    for (int q = 0; q < 32; ++q) {
      F2U v;
      v.u = __hip_atomic_load(mrow + q, __ATOMIC_RELAXED,
                              __HIP_MEMORY_SCOPE_AGENT);
      sacc = fmaf(v.f[0], wrow[2 * q], sacc);
      sacc = fmaf(v.f[1], wrow[2 * q + 1], sacc);
    }
    float* red2 = &sG[0][0];
    red2[tid] = sacc;
    __syncthreads();
    if (tid < 64) {
      float tot = fcb[(tid >> 4) & 3];
      #pragma unroll
      for (int q = 0; q < 8; ++q) tot += red2[q * 64 + tid];
      out[(g * CPG + (tid & 15)) * CLASSES + ((tid >> 4) & 3)] = tot;
    }
  }
}

extern "C" void kernel_launch(void* const* d_in, const int* in_sizes, int n_in,
                              void* d_out, int out_size, void* d_ws, size_t ws_size,
                              hipStream_t stream) {
  const int*   ids = (const int*)  d_in[0];
  const float* emb = (const float*)d_in[1];
  const float* Wf  = (const float*)d_in[2];
  const float* bf  = (const float*)d_in[3];
  const float* Wi  = (const float*)d_in[4];
  const float* bi  = (const float*)d_in[5];
  const float* Wo  = (const float*)d_in[6];
  const float* bo  = (const float*)d_in[7];
  const float* Wc  = (const float*)d_in[8];
  const float* bc  = (const float*)d_in[9];
  const float* fcw = (const float*)d_in[10];
  const float* fcb = (const float*)d_in[11];

  // zero h0 (hbuf buffer 0) and the 16KB flag region
  hipMemsetAsync(d_ws, 0, (size_t)BATCH * HIDDEN * sizeof(float), stream);
  hipMemsetAsync((char*)d_ws + (size_t)3 * BATCH * HIDDEN * sizeof(float),
                 0, 16384, stream);

  lstm_persistent<<<dim3(NBLK), dim3(NTHR), 0, stream>>>(
      ids, emb, Wf, bf, Wi, bi, Wo, bo, Wc, bc, fcw, fcb,
      (float*)d_out, (float*)d_ws);
}